// Round 18
// baseline (114.817 us; speedup 1.0000x reference)
//
#include <hip/hip_runtime.h>
#include <math.h>

#define HID_DIM  512
#define HIDH_DIM 256
#define ZBLOCKS  125
#define UBLOCKS  128   // u-fold blocks: one wave per output k
#define JC       256   // clash j-tile (LDS-staged)

typedef float fx4 __attribute__((ext_vector_type(4)));

// ---------------------------------------------------------------------------
__device__ __forceinline__ float dot4(float4 a, float4 b) {
    return a.x * b.x + a.y * b.y + a.z * b.z + a.w * b.w;
}
__device__ __forceinline__ float dotv(fx4 a, float4 b) {
    return a.x * b.x + a.y * b.y + a.z * b.z + a.w * b.w;
}

// ---------------------------------------------------------------------------
// Fused prep:
//   [0,125)      : grid-stride zero of bond_corr
//   125          : edge-dtype probe + gen_idx regularity check + cvals reduce
//   [126,254)    : u-fold, one wave per k (coalesced float4 + butterfly)
//   [254,254+GB) : xg (SoA) gather
//   [..., +MB)   : mask/gpos — one lower-bound search per thread + walk
__global__ __launch_bounds__(256) void prep_kernel(
        const unsigned int* __restrict__ ew,
        const float* __restrict__ Wp,  const float* __restrict__ bp,
        const float* __restrict__ wb,  const float* __restrict__ bb,
        const float* __restrict__ wv,  const float* __restrict__ bv,
        const int* __restrict__ gen_idx, const float* __restrict__ x_t,
        float4* __restrict__ zbase, int zcount,
        float* __restrict__ u_bond, float* __restrict__ u_val,
        float* __restrict__ cvals, int* __restrict__ flag,
        float* __restrict__ xgx, float* __restrict__ xgy, float* __restrict__ xgz,
        unsigned char* __restrict__ mask, int* __restrict__ gpos,
        int n, int G, int GB) {
    int b = blockIdx.x, t = threadIdx.x;
    if (b < ZBLOCKS) {
        const float4 z = make_float4(0.f, 0.f, 0.f, 0.f);
        for (int i = b * 256 + t; i < zcount; i += ZBLOCKS * 256) zbase[i] = z;
    } else if (b == ZBLOCKS) {
        if (t < 64) {  // wave 0: int64-vs-int32 edge layout probe
            unsigned int v = ew[2 * t + 1];
            unsigned long long bl = __ballot(v == 0u);
            if (t == 0) flag[0] = (bl == 0xFFFFFFFFFFFFFFFFULL) ? 1 : 0;
        }
        // gen_idx regularity: gen_idx[g] == g*step with pow2 step?
        __shared__ int ok;
        if (t == 0) ok = 1;
        __syncthreads();
        int step = n / G;
        int bad = (step <= 0) || ((step & (step - 1)) != 0) || (step * G != n);
        for (int g = t; g < G; g += 256)
            if (gen_idx[g] != g * step) bad = 1;
        if (bad) atomicAnd(&ok, 0);
        __syncthreads();
        if (t == 0) { flag[1] = ok; flag[2] = step - 1; }
        // cvals reduction
        __shared__ float s1[256], s2[256];
        float p1 = (t < HIDH_DIM) ? bp[t] * wb[t] : 0.f;
        float p2 = (t < HIDH_DIM) ? bp[t] * wv[t] : 0.f;
        s1[t] = p1; s2[t] = p2;
        __syncthreads();
        for (int s = 128; s > 0; s >>= 1) {
            if (t < s) { s1[t] += s1[t + s]; s2[t] += s2[t + s]; }
            __syncthreads();
        }
        if (t == 0) { cvals[0] = s1[0] + bb[0]; cvals[1] = s2[0] + bv[0]; }
    } else if (b < ZBLOCKS + 1 + UBLOCKS) {
        // one wave per output k: lanes cover the 256-wide dot coalesced
        int w = t >> 6, lane = t & 63;
        int k = (b - ZBLOCKS - 1) * 4 + w;
        if (k < HID_DIM) {
            const float* wrow = Wp + (size_t)k * HIDH_DIM;
            float4 wr = *reinterpret_cast<const float4*>(wrow + lane * 4);
            float4 vb = *reinterpret_cast<const float4*>(wb + lane * 4);
            float4 vv = *reinterpret_cast<const float4*>(wv + lane * 4);
            float ub = dot4(wr, vb);
            float uv = dot4(wr, vv);
            #pragma unroll
            for (int off = 32; off > 0; off >>= 1) {
                ub += __shfl_down(ub, off, 64);
                uv += __shfl_down(uv, off, 64);
            }
            if (lane == 0) { u_bond[k] = ub; u_val[k] = uv; }
        }
    } else if (b < ZBLOCKS + 1 + UBLOCKS + GB) {
        int g = (b - ZBLOCKS - 1 - UBLOCKS) * 256 + t;
        if (g < G) {
            int idx = gen_idx[g];
            xgx[g] = x_t[3 * idx + 0];
            xgy[g] = x_t[3 * idx + 1];
            xgz[g] = x_t[3 * idx + 2];
        }
    } else {
        // mask/gpos: thread owns i in [base, base+8). One lower-bound search,
        // then walk forward over sorted gen_idx.
        int base = ((b - ZBLOCKS - 1 - UBLOCKS - GB) * 256 + t) * 8;
        if (base >= n) return;
        int hi8 = base + 8; if (hi8 > n) hi8 = n;
        for (int i = base; i < hi8; ++i) mask[i] = 0;
        int lo = 0, hi = G;
        while (lo < hi) {
            int mid = (lo + hi) >> 1;
            if (gen_idx[mid] < base) lo = mid + 1; else hi = mid;
        }
        for (int g = lo; g < G; ++g) {
            int idx = gen_idx[g];
            if (idx >= hi8) break;
            mask[idx] = 1;
            gpos[idx] = g;
        }
    }
}

// ---------------------------------------------------------------------------
// Mega kernel v12 — stripe of 4: {0}->gate, {1,2}->bond, {3}->clash.
// Gate: 8 consecutive rows per half-wave, all 32 nt H-loads pinned in
// flight (32 KB/wave outstanding; halves gate's serial latency rounds
// vs r17). launch_bounds(256,2): VGPR cap 256 so the pinned set fits.
__global__ __launch_bounds__(256, 2) void mega_kernel(
        const float* __restrict__ H,
        const float* __restrict__ u_bond, const float* __restrict__ u_val,
        const float* __restrict__ cvals,
        const unsigned int* __restrict__ ew, const int* __restrict__ flag_p,
        const float* __restrict__ x_t, const unsigned char* __restrict__ mask,
        const float* __restrict__ xgx, const float* __restrict__ xgy,
        const float* __restrict__ xgz,
        float* __restrict__ bond_corr,
        float4* __restrict__ partials,
        float* __restrict__ bond_w, float* __restrict__ clash_w,
        int n, int E, int G, int NBG, int NBB, int NBC, int CXB) {
    __shared__ __align__(16) float sx[JC];
    __shared__ __align__(16) float sy[JC];
    __shared__ __align__(16) float sz[JC];
    int b = blockIdx.x, t = threadIdx.x;
    int stripe = b >> 2, role = b & 3;

    if (role == 0) {
        // ---- gates: 64 rows/block, 8 rows per half-wave, 32 loads deep ----
        int gb = stripe;
        if (gb >= NBG) return;
        int w = t >> 6, lane = t & 63;
        int half = lane >> 5, l = lane & 31;
        int rowA = gb * 64 + (w * 2 + half) * 8;
        if (rowA >= n) return;
        int o = l * 4;
        const float* hp[8];
        #pragma unroll
        for (int r = 0; r < 8; ++r) {
            bool v = (rowA + r < n);
            hp[r] = H + (size_t)(v ? rowA + r : rowA) * HID_DIM;
        }
        fx4 hv[8][4];
        #pragma unroll
        for (int r = 0; r < 8; ++r) {
            #pragma unroll
            for (int c = 0; c < 4; ++c)
                hv[r][c] = __builtin_nontemporal_load(
                    reinterpret_cast<const fx4*>(hp[r] + o + c * 128));
        }
        // pin all 32 loads live before any consumption (static indices ->
        // registers; per-element asm keeps regalloc from serializing)
        #pragma unroll
        for (int r = 0; r < 8; ++r) {
            #pragma unroll
            for (int c = 0; c < 4; ++c)
                asm volatile("" : "+v"(hv[r][c]));
        }
        float4 ub0 = *reinterpret_cast<const float4*>(u_bond + o);
        float4 ub1 = *reinterpret_cast<const float4*>(u_bond + o + 128);
        float4 ub2 = *reinterpret_cast<const float4*>(u_bond + o + 256);
        float4 ub3 = *reinterpret_cast<const float4*>(u_bond + o + 384);
        float4 uv0 = *reinterpret_cast<const float4*>(u_val + o);
        float4 uv1 = *reinterpret_cast<const float4*>(u_val + o + 128);
        float4 uv2 = *reinterpret_cast<const float4*>(u_val + o + 256);
        float4 uv3 = *reinterpret_cast<const float4*>(u_val + o + 384);
        float sb[8], sv[8];
        #pragma unroll
        for (int r = 0; r < 8; ++r) {
            sb[r] = dotv(hv[r][0], ub0) + dotv(hv[r][1], ub1)
                  + dotv(hv[r][2], ub2) + dotv(hv[r][3], ub3);
            sv[r] = dotv(hv[r][0], uv0) + dotv(hv[r][1], uv1)
                  + dotv(hv[r][2], uv2) + dotv(hv[r][3], uv3);
        }
        #pragma unroll
        for (int off = 16; off > 0; off >>= 1) {
            #pragma unroll
            for (int r = 0; r < 8; ++r) {
                sb[r] += __shfl_down(sb[r], off, 32);  // width=32: halves indep
                sv[r] += __shfl_down(sv[r], off, 32);
            }
        }
        if (l == 0) {
            float c0v = cvals[0], c1v = cvals[1];
            #pragma unroll
            for (int r = 0; r < 8; ++r) {
                if (rowA + r < n) {
                    bond_w [rowA + r] = 1.f / (1.f + expf(-(sb[r] + c0v)));
                    clash_w[rowA + r] = 1.f / (1.f + expf(-(sv[r] + c1v)));
                }
            }
        }
    } else if (role < 3) {
        // ---- bond scatter (256 edges/block, 1 edge/thread) ----
        int eb = stripe * 2 + (role - 1);
        if (eb >= NBB) return;
        int e = eb * 256 + t;
        if (e >= E) return;
        int f = flag_p[0];
        int row, col;
        if (f) {  // int64 layout: low words at even word indices
            row = (int)ew[2 * (size_t)e];
            col = (int)ew[2 * ((size_t)E + e)];
        } else {  // int32 layout
            row = (int)ew[e];
            col = (int)ew[(size_t)E + e];
        }
        if ((unsigned)row >= (unsigned)n || (unsigned)col >= (unsigned)n) return;
        if (flag_p[1]) {  // regular gen_idx: gate test is pure ALU
            int m = flag_p[2];
            if (((row & m) != 0) && ((col & m) != 0)) return;
        } else {
            if (!(mask[row] | mask[col])) return;
        }
        float dx = x_t[3 * row + 0] - x_t[3 * col + 0];
        float dy = x_t[3 * row + 1] - x_t[3 * col + 1];
        float dz = x_t[3 * row + 2] - x_t[3 * col + 2];
        float d2 = dx * dx + dy * dy + dz * dz;
        float dist = sqrtf(fmaxf(d2, 1e-24f)) + 1e-8f;
        float s = (dist - 1.5f) / (dist * dist);
        float fx = s * dx, fy = s * dy, fz = s * dz;
        atomicAdd(&bond_corr[3 * row + 0],  fx);
        atomicAdd(&bond_corr[3 * row + 1],  fy);
        atomicAdd(&bond_corr[3 * row + 2],  fz);
        atomicAdd(&bond_corr[3 * col + 0], -fx);
        atomicAdd(&bond_corr[3 * col + 1], -fy);
        atomicAdd(&bond_corr[3 * col + 2], -fz);
    } else {
        // ---- clash: branchless; float4 partial per (yc,i) ----
        int b2 = stripe;
        if (b2 >= NBC) return;
        int yc = b2 / CXB;
        int i  = (b2 - yc * CXB) * 256 + t;
        int j  = yc * JC + t;
        sx[t] = (j < G) ? xgx[j] : 1e30f;
        sy[t] = (j < G) ? xgy[j] : 1e30f;
        sz[t] = (j < G) ? xgz[j] : 1e30f;
        __syncthreads();
        if (i >= G) return;
        float xi = xgx[i], yi = xgy[i], zi = xgz[i];
        float csum = 0.f, cx = 0.f, cy = 0.f, cz = 0.f;
#define PROC(XS, YS, ZS) do {                                           \
            float dx = xi - (XS), dy = yi - (YS), dz = zi - (ZS);       \
            float d2 = fmaf(dx, dx, fmaf(dy, dy, dz * dz));             \
            float rm = __builtin_amdgcn_rsqf(d2);                       \
            float coef = fmaxf(fmaf(rm, rm, -rm), 0.0f);                \
            csum += coef;                                               \
            cx = fmaf(coef, (XS), cx);                                  \
            cy = fmaf(coef, (YS), cy);                                  \
            cz = fmaf(coef, (ZS), cz);                                  \
        } while (0)
        #pragma unroll 4
        for (int tt = 0; tt < JC; tt += 4) {
            float4 ax = *reinterpret_cast<const float4*>(&sx[tt]);
            float4 ay = *reinterpret_cast<const float4*>(&sy[tt]);
            float4 az = *reinterpret_cast<const float4*>(&sz[tt]);
            PROC(ax.x, ay.x, az.x);
            PROC(ax.y, ay.y, az.y);
            PROC(ax.z, ay.z, az.z);
            PROC(ax.w, ay.w, az.w);
        }
#undef PROC
        partials[(size_t)yc * G + i] = make_float4(csum, cx, cy, cz);
    }
}

// ---------------------------------------------------------------------------
// out = v_x - 0.1*bond_w*bond_corr - [mask] 0.05*clash_w*(xg*S - V),
// S,V summed from NYC coalesced float4 partials.
__global__ void final_kernel(const float* __restrict__ v_x,
                             const float* __restrict__ bond_w,
                             const float* __restrict__ clash_w,
                             const float* __restrict__ bond_corr,
                             const unsigned char* __restrict__ mask,
                             const int* __restrict__ gpos,
                             const float* __restrict__ xgx,
                             const float* __restrict__ xgy,
                             const float* __restrict__ xgz,
                             const float4* __restrict__ partials,
                             float* __restrict__ out, int n, int G, int NYC) {
    int i = blockIdx.x * blockDim.x + threadIdx.x;
    if (i >= n) return;
    float bw = 0.1f * bond_w[i];
    float ox = v_x[3 * i + 0] - bw * bond_corr[3 * i + 0];
    float oy = v_x[3 * i + 1] - bw * bond_corr[3 * i + 1];
    float oz = v_x[3 * i + 2] - bw * bond_corr[3 * i + 2];
    if (mask[i]) {
        int g = gpos[i];
        float s = 0.f, vx = 0.f, vy = 0.f, vz = 0.f;
        for (int yc = 0; yc < NYC; ++yc) {
            float4 p = partials[(size_t)yc * G + g];
            s += p.x; vx += p.y; vy += p.z; vz += p.w;
        }
        float cw = 0.05f * clash_w[i];
        ox -= cw * (xgx[g] * s - vx);
        oy -= cw * (xgy[g] * s - vy);
        oz -= cw * (xgz[g] * s - vz);
    }
    out[3 * i + 0] = ox;
    out[3 * i + 1] = oy;
    out[3 * i + 2] = oz;
}

// ---------------------------------------------------------------------------
extern "C" void kernel_launch(void* const* d_in, const int* in_sizes, int n_in,
                              void* d_out, int out_size, void* d_ws, size_t ws_size,
                              hipStream_t stream) {
    const float* v_x_raw = (const float*)d_in[0];
    const float* H       = (const float*)d_in[1];
    const float* x_t     = (const float*)d_in[2];
    const unsigned int* edges_w = (const unsigned int*)d_in[3];
    // d_in[4] = gen_mask (bool) — intentionally unused; rebuilt from gen_idx.
    const int* gen_idx   = (const int*)d_in[5];
    const float* W_proj  = (const float*)d_in[6];
    const float* b_proj  = (const float*)d_in[7];
    const float* w_bond  = (const float*)d_in[8];
    const float* b_bond  = (const float*)d_in[9];
    const float* w_val   = (const float*)d_in[10];
    const float* b_val   = (const float*)d_in[11];

    const int n = in_sizes[0] / 3;
    const int E = in_sizes[3] / 2;
    const int G = in_sizes[5];
    const int GB  = (G + 255) / 256;
    const int NYC = (G + JC - 1) / JC;   // clash y-chunks (32)

    char* ws = (char*)d_ws;
    // --- zeroed region (bond_corr only) ---
    float* bond_corr = (float*)(ws);
    size_t zbytes = (size_t)n * 12;
    size_t off = (zbytes + 15) & ~(size_t)15;
    int zcount = (int)(off / 16);
    // --- write-every-launch region ---
    unsigned char* mask = (unsigned char*)(ws + off); off += ((size_t)n + 15) & ~(size_t)15;
    int*   gpos    = (int*)(ws + off);                off += (size_t)n * 4;
    float* bond_w  = (float*)(ws + off);              off += (size_t)n * 4;
    float* clash_w = (float*)(ws + off);              off += (size_t)n * 4;
    float* u_bond  = (float*)(ws + off);              off += HID_DIM * 4;
    float* u_val   = (float*)(ws + off);              off += HID_DIM * 4;
    float* cvals   = (float*)(ws + off);              off += 16;
    int*   flag    = (int*)(ws + off);                off += 16;
    float* xgx     = (float*)(ws + off);              off += (size_t)G * 4;
    float* xgy     = (float*)(ws + off);              off += (size_t)G * 4;
    float* xgz     = (float*)(ws + off);              off += (size_t)G * 4;
    float4* partials = (float4*)(ws + off);           off += (size_t)NYC * G * 16;

    const int MB  = (n + 2047) / 2048;   // mask/gpos blocks (8 idx/thread)
    const int CXB = GB;                   // clash x-blocks
    const int NBC = CXB * NYC;            // clash blocks (1024)
    const int NBG = (n + 63) / 64;        // gate blocks (1024, 64 rows each)
    const int NBB = (E + 255) / 256;      // bond blocks (2048)

    // stripes of 4: 1 gate + 2 bond + 1 clash
    int S = NBG;
    if ((NBB + 1) / 2 > S) S = (NBB + 1) / 2;
    if (NBC > S) S = NBC;

    prep_kernel<<<ZBLOCKS + 1 + UBLOCKS + GB + MB, 256, 0, stream>>>(
        edges_w, W_proj, b_proj, w_bond, b_bond, w_val, b_val,
        gen_idx, x_t, (float4*)ws, zcount,
        u_bond, u_val, cvals, flag, xgx, xgy, xgz, mask, gpos, n, G, GB);

    mega_kernel<<<S * 4, 256, 0, stream>>>(
        H, u_bond, u_val, cvals, edges_w, flag, x_t, mask,
        xgx, xgy, xgz, bond_corr, partials, bond_w, clash_w,
        n, E, G, NBG, NBB, NBC, CXB);

    final_kernel<<<(n + 255) / 256, 256, 0, stream>>>(
        v_x_raw, bond_w, clash_w, bond_corr, mask, gpos,
        xgx, xgy, xgz, partials, (float*)d_out, n, G, NYC);
}

// Round 19
// 83.465 us; speedup vs baseline: 1.3756x; 1.3756x over previous
//
#include <hip/hip_runtime.h>
#include <math.h>

#define HID_DIM  512
#define HIDH_DIM 256
#define ZBLOCKS  125
#define UBLOCKS  128   // u-fold blocks: one wave per output k
#define JC       256   // clash j-tile (LDS-staged)

typedef float fx4 __attribute__((ext_vector_type(4)));

// ---------------------------------------------------------------------------
__device__ __forceinline__ float dot4(float4 a, float4 b) {
    return a.x * b.x + a.y * b.y + a.z * b.z + a.w * b.w;
}
__device__ __forceinline__ float dotv(fx4 a, float4 b) {
    return a.x * b.x + a.y * b.y + a.z * b.z + a.w * b.w;
}

// ---------------------------------------------------------------------------
// Fused prep:
//   [0,125)      : grid-stride zero of bond_corr
//   125          : edge-dtype probe + gen_idx regularity check + cvals reduce
//   [126,254)    : u-fold, one wave per k (coalesced float4 + butterfly)
//   [254,254+GB) : xg (SoA) gather
//   [..., +MB)   : mask/gpos — one lower-bound search per thread + walk
__global__ __launch_bounds__(256) void prep_kernel(
        const unsigned int* __restrict__ ew,
        const float* __restrict__ Wp,  const float* __restrict__ bp,
        const float* __restrict__ wb,  const float* __restrict__ bb,
        const float* __restrict__ wv,  const float* __restrict__ bv,
        const int* __restrict__ gen_idx, const float* __restrict__ x_t,
        float4* __restrict__ zbase, int zcount,
        float* __restrict__ u_bond, float* __restrict__ u_val,
        float* __restrict__ cvals, int* __restrict__ flag,
        float* __restrict__ xgx, float* __restrict__ xgy, float* __restrict__ xgz,
        unsigned char* __restrict__ mask, int* __restrict__ gpos,
        int n, int G, int GB) {
    int b = blockIdx.x, t = threadIdx.x;
    if (b < ZBLOCKS) {
        const float4 z = make_float4(0.f, 0.f, 0.f, 0.f);
        for (int i = b * 256 + t; i < zcount; i += ZBLOCKS * 256) zbase[i] = z;
    } else if (b == ZBLOCKS) {
        if (t < 64) {  // wave 0: int64-vs-int32 edge layout probe
            unsigned int v = ew[2 * t + 1];
            unsigned long long bl = __ballot(v == 0u);
            if (t == 0) flag[0] = (bl == 0xFFFFFFFFFFFFFFFFULL) ? 1 : 0;
        }
        // gen_idx regularity: gen_idx[g] == g*step with pow2 step?
        __shared__ int ok;
        if (t == 0) ok = 1;
        __syncthreads();
        int step = n / G;
        int bad = (step <= 0) || ((step & (step - 1)) != 0) || (step * G != n);
        for (int g = t; g < G; g += 256)
            if (gen_idx[g] != g * step) bad = 1;
        if (bad) atomicAnd(&ok, 0);
        __syncthreads();
        if (t == 0) { flag[1] = ok; flag[2] = step - 1; }
        // cvals reduction
        __shared__ float s1[256], s2[256];
        float p1 = (t < HIDH_DIM) ? bp[t] * wb[t] : 0.f;
        float p2 = (t < HIDH_DIM) ? bp[t] * wv[t] : 0.f;
        s1[t] = p1; s2[t] = p2;
        __syncthreads();
        for (int s = 128; s > 0; s >>= 1) {
            if (t < s) { s1[t] += s1[t + s]; s2[t] += s2[t + s]; }
            __syncthreads();
        }
        if (t == 0) { cvals[0] = s1[0] + bb[0]; cvals[1] = s2[0] + bv[0]; }
    } else if (b < ZBLOCKS + 1 + UBLOCKS) {
        // one wave per output k: lanes cover the 256-wide dot coalesced
        int w = t >> 6, lane = t & 63;
        int k = (b - ZBLOCKS - 1) * 4 + w;
        if (k < HID_DIM) {
            const float* wrow = Wp + (size_t)k * HIDH_DIM;
            float4 wr = *reinterpret_cast<const float4*>(wrow + lane * 4);
            float4 vb = *reinterpret_cast<const float4*>(wb + lane * 4);
            float4 vv = *reinterpret_cast<const float4*>(wv + lane * 4);
            float ub = dot4(wr, vb);
            float uv = dot4(wr, vv);
            #pragma unroll
            for (int off = 32; off > 0; off >>= 1) {
                ub += __shfl_down(ub, off, 64);
                uv += __shfl_down(uv, off, 64);
            }
            if (lane == 0) { u_bond[k] = ub; u_val[k] = uv; }
        }
    } else if (b < ZBLOCKS + 1 + UBLOCKS + GB) {
        int g = (b - ZBLOCKS - 1 - UBLOCKS) * 256 + t;
        if (g < G) {
            int idx = gen_idx[g];
            xgx[g] = x_t[3 * idx + 0];
            xgy[g] = x_t[3 * idx + 1];
            xgz[g] = x_t[3 * idx + 2];
        }
    } else {
        // mask/gpos: thread owns i in [base, base+8). One lower-bound search,
        // then walk forward over sorted gen_idx.
        int base = ((b - ZBLOCKS - 1 - UBLOCKS - GB) * 256 + t) * 8;
        if (base >= n) return;
        int hi8 = base + 8; if (hi8 > n) hi8 = n;
        for (int i = base; i < hi8; ++i) mask[i] = 0;
        int lo = 0, hi = G;
        while (lo < hi) {
            int mid = (lo + hi) >> 1;
            if (gen_idx[mid] < base) lo = mid + 1; else hi = mid;
        }
        for (int g = lo; g < G; ++g) {
            int idx = gen_idx[g];
            if (idx >= hi8) break;
            mask[idx] = 1;
            gpos[idx] = g;
        }
    }
}

// ---------------------------------------------------------------------------
// Mega kernel v11 (r17 best) — stripe of 5: {0,1}->gate, {2,3}->bond,
// {4}->clash. Gate: 4 consecutive rows per half-wave, all 16 nt H-loads
// pinned in flight before any consumption.
__global__ __launch_bounds__(256) void mega_kernel(
        const float* __restrict__ H,
        const float* __restrict__ u_bond, const float* __restrict__ u_val,
        const float* __restrict__ cvals,
        const unsigned int* __restrict__ ew, const int* __restrict__ flag_p,
        const float* __restrict__ x_t, const unsigned char* __restrict__ mask,
        const float* __restrict__ xgx, const float* __restrict__ xgy,
        const float* __restrict__ xgz,
        float* __restrict__ bond_corr,
        float4* __restrict__ partials,
        float* __restrict__ bond_w, float* __restrict__ clash_w,
        int n, int E, int G, int NBG, int NBB, int NBC, int CXB) {
    __shared__ __align__(16) float sx[JC];
    __shared__ __align__(16) float sy[JC];
    __shared__ __align__(16) float sz[JC];
    int b = blockIdx.x, t = threadIdx.x;
    int stripe = b / 5, role = b - stripe * 5;

    if (role < 2) {
        // ---- gates: 32 rows/block, 4 rows per half-wave, 16 loads deep ----
        int gb = stripe * 2 + role;
        if (gb >= NBG) return;
        int w = t >> 6, lane = t & 63;
        int half = lane >> 5, l = lane & 31;
        int rowA = gb * 32 + (w * 2 + half) * 4;
        if (rowA >= n) return;
        bool v1 = (rowA + 1 < n), v2 = (rowA + 2 < n), v3 = (rowA + 3 < n);
        const float* h0 = H + (size_t)rowA * HID_DIM;
        const float* h1 = h0 + (v1 ? HID_DIM : 0);
        const float* h2 = h0 + (v2 ? 2 * HID_DIM : 0);
        const float* h3 = h0 + (v3 ? 3 * HID_DIM : 0);
        int o = l * 4;
        fx4 a0 = __builtin_nontemporal_load(reinterpret_cast<const fx4*>(h0 + o));
        fx4 a1 = __builtin_nontemporal_load(reinterpret_cast<const fx4*>(h0 + o + 128));
        fx4 a2 = __builtin_nontemporal_load(reinterpret_cast<const fx4*>(h0 + o + 256));
        fx4 a3 = __builtin_nontemporal_load(reinterpret_cast<const fx4*>(h0 + o + 384));
        fx4 b0 = __builtin_nontemporal_load(reinterpret_cast<const fx4*>(h1 + o));
        fx4 b1 = __builtin_nontemporal_load(reinterpret_cast<const fx4*>(h1 + o + 128));
        fx4 b2 = __builtin_nontemporal_load(reinterpret_cast<const fx4*>(h1 + o + 256));
        fx4 b3 = __builtin_nontemporal_load(reinterpret_cast<const fx4*>(h1 + o + 384));
        fx4 c0 = __builtin_nontemporal_load(reinterpret_cast<const fx4*>(h2 + o));
        fx4 c1 = __builtin_nontemporal_load(reinterpret_cast<const fx4*>(h2 + o + 128));
        fx4 c2 = __builtin_nontemporal_load(reinterpret_cast<const fx4*>(h2 + o + 256));
        fx4 c3 = __builtin_nontemporal_load(reinterpret_cast<const fx4*>(h2 + o + 384));
        fx4 d0 = __builtin_nontemporal_load(reinterpret_cast<const fx4*>(h3 + o));
        fx4 d1 = __builtin_nontemporal_load(reinterpret_cast<const fx4*>(h3 + o + 128));
        fx4 d2 = __builtin_nontemporal_load(reinterpret_cast<const fx4*>(h3 + o + 256));
        fx4 d3 = __builtin_nontemporal_load(reinterpret_cast<const fx4*>(h3 + o + 384));
        // pin all 16 row-loads live before any consumption
        asm volatile("" : "+v"(a0), "+v"(a1), "+v"(a2), "+v"(a3));
        asm volatile("" : "+v"(b0), "+v"(b1), "+v"(b2), "+v"(b3));
        asm volatile("" : "+v"(c0), "+v"(c1), "+v"(c2), "+v"(c3));
        asm volatile("" : "+v"(d0), "+v"(d1), "+v"(d2), "+v"(d3));
        float4 ub0 = *reinterpret_cast<const float4*>(u_bond + o);
        float4 ub1 = *reinterpret_cast<const float4*>(u_bond + o + 128);
        float4 ub2 = *reinterpret_cast<const float4*>(u_bond + o + 256);
        float4 ub3 = *reinterpret_cast<const float4*>(u_bond + o + 384);
        float4 uv0 = *reinterpret_cast<const float4*>(u_val + o);
        float4 uv1 = *reinterpret_cast<const float4*>(u_val + o + 128);
        float4 uv2 = *reinterpret_cast<const float4*>(u_val + o + 256);
        float4 uv3 = *reinterpret_cast<const float4*>(u_val + o + 384);
        float sb0 = dotv(a0, ub0) + dotv(a1, ub1) + dotv(a2, ub2) + dotv(a3, ub3);
        float sv0 = dotv(a0, uv0) + dotv(a1, uv1) + dotv(a2, uv2) + dotv(a3, uv3);
        float sb1 = dotv(b0, ub0) + dotv(b1, ub1) + dotv(b2, ub2) + dotv(b3, ub3);
        float sv1 = dotv(b0, uv0) + dotv(b1, uv1) + dotv(b2, uv2) + dotv(b3, uv3);
        float sb2 = dotv(c0, ub0) + dotv(c1, ub1) + dotv(c2, ub2) + dotv(c3, ub3);
        float sv2 = dotv(c0, uv0) + dotv(c1, uv1) + dotv(c2, uv2) + dotv(c3, uv3);
        float sb3 = dotv(d0, ub0) + dotv(d1, ub1) + dotv(d2, ub2) + dotv(d3, ub3);
        float sv3 = dotv(d0, uv0) + dotv(d1, uv1) + dotv(d2, uv2) + dotv(d3, uv3);
        #pragma unroll
        for (int off = 16; off > 0; off >>= 1) {
            sb0 += __shfl_down(sb0, off, 32);   // width=32: halves independent
            sv0 += __shfl_down(sv0, off, 32);
            sb1 += __shfl_down(sb1, off, 32);
            sv1 += __shfl_down(sv1, off, 32);
            sb2 += __shfl_down(sb2, off, 32);
            sv2 += __shfl_down(sv2, off, 32);
            sb3 += __shfl_down(sb3, off, 32);
            sv3 += __shfl_down(sv3, off, 32);
        }
        if (l == 0) {
            float c0v = cvals[0], c1v = cvals[1];
            bond_w [rowA] = 1.f / (1.f + expf(-(sb0 + c0v)));
            clash_w[rowA] = 1.f / (1.f + expf(-(sv0 + c1v)));
            if (v1) {
                bond_w [rowA + 1] = 1.f / (1.f + expf(-(sb1 + c0v)));
                clash_w[rowA + 1] = 1.f / (1.f + expf(-(sv1 + c1v)));
            }
            if (v2) {
                bond_w [rowA + 2] = 1.f / (1.f + expf(-(sb2 + c0v)));
                clash_w[rowA + 2] = 1.f / (1.f + expf(-(sv2 + c1v)));
            }
            if (v3) {
                bond_w [rowA + 3] = 1.f / (1.f + expf(-(sb3 + c0v)));
                clash_w[rowA + 3] = 1.f / (1.f + expf(-(sv3 + c1v)));
            }
        }
    } else if (role < 4) {
        // ---- bond scatter (256 edges/block, 1 edge/thread) ----
        int eb = stripe * 2 + (role - 2);
        if (eb >= NBB) return;
        int e = eb * 256 + t;
        if (e >= E) return;
        int f = flag_p[0];
        int row, col;
        if (f) {  // int64 layout: low words at even word indices
            row = (int)ew[2 * (size_t)e];
            col = (int)ew[2 * ((size_t)E + e)];
        } else {  // int32 layout
            row = (int)ew[e];
            col = (int)ew[(size_t)E + e];
        }
        if ((unsigned)row >= (unsigned)n || (unsigned)col >= (unsigned)n) return;
        if (flag_p[1]) {  // regular gen_idx: gate test is pure ALU
            int m = flag_p[2];
            if (((row & m) != 0) && ((col & m) != 0)) return;
        } else {
            if (!(mask[row] | mask[col])) return;
        }
        float dx = x_t[3 * row + 0] - x_t[3 * col + 0];
        float dy = x_t[3 * row + 1] - x_t[3 * col + 1];
        float dz = x_t[3 * row + 2] - x_t[3 * col + 2];
        float d2 = dx * dx + dy * dy + dz * dz;
        float dist = sqrtf(fmaxf(d2, 1e-24f)) + 1e-8f;
        float s = (dist - 1.5f) / (dist * dist);
        float fx = s * dx, fy = s * dy, fz = s * dz;
        atomicAdd(&bond_corr[3 * row + 0],  fx);
        atomicAdd(&bond_corr[3 * row + 1],  fy);
        atomicAdd(&bond_corr[3 * row + 2],  fz);
        atomicAdd(&bond_corr[3 * col + 0], -fx);
        atomicAdd(&bond_corr[3 * col + 1], -fy);
        atomicAdd(&bond_corr[3 * col + 2], -fz);
    } else {
        // ---- clash: branchless; float4 partial per (yc,i) ----
        int b2 = stripe;
        if (b2 >= NBC) return;
        int yc = b2 / CXB;
        int i  = (b2 - yc * CXB) * 256 + t;
        int j  = yc * JC + t;
        sx[t] = (j < G) ? xgx[j] : 1e30f;
        sy[t] = (j < G) ? xgy[j] : 1e30f;
        sz[t] = (j < G) ? xgz[j] : 1e30f;
        __syncthreads();
        if (i >= G) return;
        float xi = xgx[i], yi = xgy[i], zi = xgz[i];
        float csum = 0.f, cx = 0.f, cy = 0.f, cz = 0.f;
#define PROC(XS, YS, ZS) do {                                           \
            float dx = xi - (XS), dy = yi - (YS), dz = zi - (ZS);       \
            float d2 = fmaf(dx, dx, fmaf(dy, dy, dz * dz));             \
            float rm = __builtin_amdgcn_rsqf(d2);                       \
            float coef = fmaxf(fmaf(rm, rm, -rm), 0.0f);                \
            csum += coef;                                               \
            cx = fmaf(coef, (XS), cx);                                  \
            cy = fmaf(coef, (YS), cy);                                  \
            cz = fmaf(coef, (ZS), cz);                                  \
        } while (0)
        #pragma unroll 4
        for (int tt = 0; tt < JC; tt += 4) {
            float4 ax = *reinterpret_cast<const float4*>(&sx[tt]);
            float4 ay = *reinterpret_cast<const float4*>(&sy[tt]);
            float4 az = *reinterpret_cast<const float4*>(&sz[tt]);
            PROC(ax.x, ay.x, az.x);
            PROC(ax.y, ay.y, az.y);
            PROC(ax.z, ay.z, az.z);
            PROC(ax.w, ay.w, az.w);
        }
#undef PROC
        partials[(size_t)yc * G + i] = make_float4(csum, cx, cy, cz);
    }
}

// ---------------------------------------------------------------------------
// out = v_x - 0.1*bond_w*bond_corr - [mask] 0.05*clash_w*(xg*S - V),
// S,V summed from NYC coalesced float4 partials.
__global__ void final_kernel(const float* __restrict__ v_x,
                             const float* __restrict__ bond_w,
                             const float* __restrict__ clash_w,
                             const float* __restrict__ bond_corr,
                             const unsigned char* __restrict__ mask,
                             const int* __restrict__ gpos,
                             const float* __restrict__ xgx,
                             const float* __restrict__ xgy,
                             const float* __restrict__ xgz,
                             const float4* __restrict__ partials,
                             float* __restrict__ out, int n, int G, int NYC) {
    int i = blockIdx.x * blockDim.x + threadIdx.x;
    if (i >= n) return;
    float bw = 0.1f * bond_w[i];
    float ox = v_x[3 * i + 0] - bw * bond_corr[3 * i + 0];
    float oy = v_x[3 * i + 1] - bw * bond_corr[3 * i + 1];
    float oz = v_x[3 * i + 2] - bw * bond_corr[3 * i + 2];
    if (mask[i]) {
        int g = gpos[i];
        float s = 0.f, vx = 0.f, vy = 0.f, vz = 0.f;
        for (int yc = 0; yc < NYC; ++yc) {
            float4 p = partials[(size_t)yc * G + g];
            s += p.x; vx += p.y; vy += p.z; vz += p.w;
        }
        float cw = 0.05f * clash_w[i];
        ox -= cw * (xgx[g] * s - vx);
        oy -= cw * (xgy[g] * s - vy);
        oz -= cw * (xgz[g] * s - vz);
    }
    out[3 * i + 0] = ox;
    out[3 * i + 1] = oy;
    out[3 * i + 2] = oz;
}

// ---------------------------------------------------------------------------
extern "C" void kernel_launch(void* const* d_in, const int* in_sizes, int n_in,
                              void* d_out, int out_size, void* d_ws, size_t ws_size,
                              hipStream_t stream) {
    const float* v_x_raw = (const float*)d_in[0];
    const float* H       = (const float*)d_in[1];
    const float* x_t     = (const float*)d_in[2];
    const unsigned int* edges_w = (const unsigned int*)d_in[3];
    // d_in[4] = gen_mask (bool) — intentionally unused; rebuilt from gen_idx.
    const int* gen_idx   = (const int*)d_in[5];
    const float* W_proj  = (const float*)d_in[6];
    const float* b_proj  = (const float*)d_in[7];
    const float* w_bond  = (const float*)d_in[8];
    const float* b_bond  = (const float*)d_in[9];
    const float* w_val   = (const float*)d_in[10];
    const float* b_val   = (const float*)d_in[11];

    const int n = in_sizes[0] / 3;
    const int E = in_sizes[3] / 2;
    const int G = in_sizes[5];
    const int GB  = (G + 255) / 256;
    const int NYC = (G + JC - 1) / JC;   // clash y-chunks (32)

    char* ws = (char*)d_ws;
    // --- zeroed region (bond_corr only) ---
    float* bond_corr = (float*)(ws);
    size_t zbytes = (size_t)n * 12;
    size_t off = (zbytes + 15) & ~(size_t)15;
    int zcount = (int)(off / 16);
    // --- write-every-launch region ---
    unsigned char* mask = (unsigned char*)(ws + off); off += ((size_t)n + 15) & ~(size_t)15;
    int*   gpos    = (int*)(ws + off);                off += (size_t)n * 4;
    float* bond_w  = (float*)(ws + off);              off += (size_t)n * 4;
    float* clash_w = (float*)(ws + off);              off += (size_t)n * 4;
    float* u_bond  = (float*)(ws + off);              off += HID_DIM * 4;
    float* u_val   = (float*)(ws + off);              off += HID_DIM * 4;
    float* cvals   = (float*)(ws + off);              off += 16;
    int*   flag    = (int*)(ws + off);                off += 16;
    float* xgx     = (float*)(ws + off);              off += (size_t)G * 4;
    float* xgy     = (float*)(ws + off);              off += (size_t)G * 4;
    float* xgz     = (float*)(ws + off);              off += (size_t)G * 4;
    float4* partials = (float4*)(ws + off);           off += (size_t)NYC * G * 16;

    const int MB  = (n + 2047) / 2048;   // mask/gpos blocks (8 idx/thread)
    const int CXB = GB;                   // clash x-blocks
    const int NBC = CXB * NYC;            // clash blocks (1024)
    const int NBG = (n + 31) / 32;        // gate blocks (2048, 32 rows each)
    const int NBB = (E + 255) / 256;      // bond blocks (2048)

    // stripes of 5: 2 gate + 2 bond + 1 clash
    int S = (NBG + 1) / 2;
    if ((NBB + 1) / 2 > S) S = (NBB + 1) / 2;
    if (NBC > S) S = NBC;

    prep_kernel<<<ZBLOCKS + 1 + UBLOCKS + GB + MB, 256, 0, stream>>>(
        edges_w, W_proj, b_proj, w_bond, b_bond, w_val, b_val,
        gen_idx, x_t, (float4*)ws, zcount,
        u_bond, u_val, cvals, flag, xgx, xgy, xgz, mask, gpos, n, G, GB);

    mega_kernel<<<S * 5, 256, 0, stream>>>(
        H, u_bond, u_val, cvals, edges_w, flag, x_t, mask,
        xgx, xgy, xgz, bond_corr, partials, bond_w, clash_w,
        n, E, G, NBG, NBB, NBC, CXB);

    final_kernel<<<(n + 255) / 256, 256, 0, stream>>>(
        v_x_raw, bond_w, clash_w, bond_corr, mask, gpos,
        xgx, xgy, xgz, partials, (float*)d_out, n, G, NYC);
}